// Round 16
// baseline (245.984 us; speedup 1.0000x reference)
//
#include <hip/hip_runtime.h>

// Problem constants
#define BB    32
#define CC    64
#define MM    8
#define NSP   16384            // H*W = 128*128
#define CNTF  524288.0f        // B*N, BN statistics count
#define NBLK1 512              // k_fused1 grid: 2 blocks/CU (launch_bounds-forced), co-resident

typedef float f32x4 __attribute__((ext_vector_type(4)));
typedef unsigned int u32x2 __attribute__((ext_vector_type(2)));

// Workspace layout (BYTE offsets)
#define OFF_FXP_B    0ull                               // [B][M][N] bf16, 8.39 MB
#define OFF_PSTATS_B 8388608ull                         // [512][32] f32 per-block stats partials
#define OFF_PWSA_B   (OFF_PSTATS_B + 512ull*32*4)       // [512][3][64] f32 gram partials
#define OFF_STATS_B  (OFF_PWSA_B + 512ull*192*4)        // [32] f32 final stats
#define OFF_BAR_B    (OFF_STATS_B + 32ull*4)            // [1] u32 barrier counter

// bf16 pack (round-to-nearest-even) / unpack helpers
__device__ __forceinline__ unsigned pk_bf2(float a, float b) {
    unsigned ua = __float_as_uint(a); ua += 0x7FFFu + ((ua >> 16) & 1u);
    unsigned ub = __float_as_uint(b); ub += 0x7FFFu + ((ub >> 16) & 1u);
    return (ua >> 16) | (ub & 0xFFFF0000u);
}
__device__ __forceinline__ float lo16(unsigned u) { return __uint_as_float(u << 16); }
__device__ __forceinline__ float hi16(unsigned u) { return __uint_as_float(u & 0xFFFF0000u); }

__device__ __forceinline__ float agent_loadf(const float* p) {
    return __hip_atomic_load(p, __ATOMIC_RELAXED, __HIP_MEMORY_SCOPE_AGENT);
}
__device__ __forceinline__ void agent_storef(float* p, float v) {
    __hip_atomic_store(p, v, __ATOMIC_RELAXED, __HIP_MEMORY_SCOPE_AGENT);
}

// Manual grid barrier (R7-proven): counter zeroed by 4-byte host memset each launch.
__device__ __forceinline__ void grid_barrier(int* cnt) {
    __syncthreads();
    if (threadIdx.x == 0) {
        __threadfence();
        __hip_atomic_fetch_add(cnt, 1, __ATOMIC_ACQ_REL, __HIP_MEMORY_SCOPE_AGENT);
        while (__hip_atomic_load(cnt, __ATOMIC_ACQUIRE, __HIP_MEMORY_SCOPE_AGENT) < NBLK1)
            __builtin_amdgcn_s_sleep(1);
        __threadfence();
    }
    __syncthreads();
}

#define AXPY(A, WS, XV) \
    (A).x = fmaf((WS), (XV).x, (A).x); (A).y = fmaf((WS), (XV).y, (A).y); \
    (A).z = fmaf((WS), (XV).z, (A).z); (A).w = fmaf((WS), (XV).w, (A).w);

// 32-value wave reduce-scatter butterfly (5 stages within 32-lane groups,
// then xor-32 combine). Lane l<32 atomically adds total of acc[bitrev5(l)].
#define BUTTERFLY32_ATOMIC(OFFSET) { \
    _Pragma("unroll") for (int s2 = 0; s2 < 5; ++s2) { \
        int half = 16 >> s2; int up = (lane >> s2) & 1; \
        _Pragma("unroll") for (int j = 0; j < 16; ++j) { \
            if (j >= half) break; \
            float send = up ? acc[j] : acc[j + half]; \
            float recv = __shfl_xor(send, 1 << s2); \
            float keep = up ? acc[j + half] : acc[j]; \
            acc[j] = keep + recv; } } \
    float tot = acc[0] + __shfl_xor(acc[0], 32); \
    if (lane < 32) atomicAdd(&sacc[(OFFSET) + (__brev((unsigned)lane) >> 27)], tot); }

// ---------------------------------------------------------------------------
// K1: fused conv + BN-stats + grid-barrier + in-register Gram.
// grid 512 x 256, launch_bounds(256,2): the PROVEN no-spill shape (R5/R12
// k_conv) — 256-VGPR cap, 2 blocks/CU, all 512 blocks co-resident.
// Phase 1: conv accumulate (fp32 regs), fxp->bf16 store, stats partial.
// Barrier. Phase 2: reduce stats, BN+ReLU the live registers, accumulate
// Wsf/Wsg/Cross in acc[32] halves, butterfly, store per-block partials.
// gxp/hx never touch memory.
__global__ __launch_bounds__(256, 2) void k_fused1(const float* __restrict__ x,
        const float* __restrict__ fw, const float* __restrict__ gw,
        const float* __restrict__ hw,
        const float* __restrict__ fb, const float* __restrict__ gb,
        const float* __restrict__ hb,
        const float* __restrict__ fgam, const float* __restrict__ fbet,
        const float* __restrict__ ggam, const float* __restrict__ gbet,
        char* __restrict__ wsb) {
    __shared__ float wt[1536];          // [c][24]: f0..7 g0..7 h0..7
    __shared__ float sred[4][32];
    __shared__ float sst[8][32];
    __shared__ float stot[32];
    __shared__ float sacc[192];

    for (int i = threadIdx.x; i < 1536; i += 256) {
        int c = i / 24, k = i % 24;
        wt[i] = (k < 8) ? fw[k * 64 + c]
              : (k < 16) ? gw[(k - 8) * 64 + c]
                         : hw[(k - 16) * 64 + c];
    }
    if (threadIdx.x < 192) sacc[threadIdx.x] = 0.f;
    __syncthreads();

    int g  = blockIdx.x * 256 + threadIdx.x;   // quad index (4 n per thread)
    int b  = g >> 12;                          // 4096 quads per batch (16 blocks/batch)
    int n0 = (g & 4095) * 4;
    int wid = threadIdx.x >> 6, lane = threadIdx.x & 63;

    const float* xp = x + (size_t)b * CC * NSP + n0;

    // ---- Phase 1: conv accumulate ----
    float4 af[8], ag[8], ah[8];
#pragma unroll
    for (int m = 0; m < 8; ++m) {
        float bf = fb[m], bg = gb[m], bh = hb[m];
        af[m] = make_float4(bf, bf, bf, bf);
        ag[m] = make_float4(bg, bg, bg, bg);
        ah[m] = make_float4(bh, bh, bh, bh);
    }
#pragma unroll 8
    for (int c = 0; c < 64; ++c) {
        float4 xv = *(const float4*)(xp + (size_t)c * NSP);
        const float4* w4 = (const float4*)(&wt[c * 24]);
        float4 wf0 = w4[0], wf1 = w4[1], wg0 = w4[2], wg1 = w4[3], wh0 = w4[4], wh1 = w4[5];
        AXPY(af[0], wf0.x, xv); AXPY(af[1], wf0.y, xv); AXPY(af[2], wf0.z, xv); AXPY(af[3], wf0.w, xv);
        AXPY(af[4], wf1.x, xv); AXPY(af[5], wf1.y, xv); AXPY(af[6], wf1.z, xv); AXPY(af[7], wf1.w, xv);
        AXPY(ag[0], wg0.x, xv); AXPY(ag[1], wg0.y, xv); AXPY(ag[2], wg0.z, xv); AXPY(ag[3], wg0.w, xv);
        AXPY(ag[4], wg1.x, xv); AXPY(ag[5], wg1.y, xv); AXPY(ag[6], wg1.z, xv); AXPY(ag[7], wg1.w, xv);
        AXPY(ah[0], wh0.x, xv); AXPY(ah[1], wh0.y, xv); AXPY(ah[2], wh0.z, xv); AXPY(ah[3], wh0.w, xv);
        AXPY(ah[4], wh1.x, xv); AXPY(ah[5], wh1.y, xv); AXPY(ah[6], wh1.z, xv); AXPY(ah[7], wh1.w, xv);
    }

    // fxp -> bf16 (k_out's only bulk input); gxp/hx never stored
    {
        unsigned short* fx16 = (unsigned short*)(wsb + OFF_FXP_B);
        size_t base = (size_t)b * MM * NSP + n0;
#pragma unroll
        for (int m = 0; m < 8; ++m) {
            u32x2 pf; pf.x = pk_bf2(af[m].x, af[m].y); pf.y = pk_bf2(af[m].z, af[m].w);
            *(u32x2*)(fx16 + base + (size_t)m * NSP) = pf;
        }
    }

    // BN stats from registers -> per-block partial (device-scope stores)
#pragma unroll
    for (int m = 0; m < 8; ++m) {
        float fs = af[m].x + af[m].y + af[m].z + af[m].w;
        float fq = af[m].x * af[m].x + af[m].y * af[m].y + af[m].z * af[m].z + af[m].w * af[m].w;
        float gs = ag[m].x + ag[m].y + ag[m].z + ag[m].w;
        float gq = ag[m].x * ag[m].x + ag[m].y * ag[m].y + ag[m].z * ag[m].z + ag[m].w * ag[m].w;
#pragma unroll
        for (int o = 1; o < 64; o <<= 1) {
            fs += __shfl_xor(fs, o); fq += __shfl_xor(fq, o);
            gs += __shfl_xor(gs, o); gq += __shfl_xor(gq, o);
        }
        if (lane == 0) {
            sred[wid][m] = fs; sred[wid][8 + m] = fq;
            sred[wid][16 + m] = gs; sred[wid][24 + m] = gq;
        }
    }
    __syncthreads();
    if (threadIdx.x < 32) {
        float t = sred[0][threadIdx.x] + sred[1][threadIdx.x]
                + sred[2][threadIdx.x] + sred[3][threadIdx.x];
        agent_storef((float*)(wsb + OFF_PSTATS_B) + blockIdx.x * 32 + threadIdx.x, t);
    }

    grid_barrier((int*)(wsb + OFF_BAR_B));    // ---- stats final ----

    // ---- Phase 2a: reduce the 512 stats partials (L2-hot) ----
    {
        int t32 = threadIdx.x & 31, seg = threadIdx.x >> 5;   // 8 segs x 64 blocks
        const float* ps = (const float*)(wsb + OFF_PSTATS_B);
        float s = 0.f;
#pragma unroll 8
        for (int i = 0; i < 64; ++i) s += agent_loadf(ps + (seg * 64 + i) * 32 + t32);
        sst[seg][t32] = s;
    }
    __syncthreads();
    if (threadIdx.x < 32) {
        float t = 0.f;
#pragma unroll
        for (int w = 0; w < 8; ++w) t += sst[w][threadIdx.x];
        stot[threadIdx.x] = t;
        if (blockIdx.x == 0) ((float*)(wsb + OFF_STATS_B))[threadIdx.x] = t;
    }
    __syncthreads();

    const float inv = 1.f / CNTF;

    // ---- Phase 2b: Wsf from af (fp32 registers) ----
    {
        float scf[8], off_f[8];
#pragma unroll
        for (int m = 0; m < 8; ++m) {
            float mean = stot[m] * inv;
            float var  = stot[8 + m] * inv - mean * mean;
            float s = fgam[m] / sqrtf(var + 1e-5f);
            scf[m] = s; off_f[m] = fbet[m] - mean * s;
        }
        float fnx[8], fny[8], fnz[8], fnw[8];
#pragma unroll
        for (int m = 0; m < 8; ++m) {
            float t;
            t = fmaf(scf[m], af[m].x, off_f[m]); fnx[m] = t > 0.f ? t : 0.f;
            t = fmaf(scf[m], af[m].y, off_f[m]); fny[m] = t > 0.f ? t : 0.f;
            t = fmaf(scf[m], af[m].z, off_f[m]); fnz[m] = t > 0.f ? t : 0.f;
            t = fmaf(scf[m], af[m].w, off_f[m]); fnw[m] = t > 0.f ? t : 0.f;
        }
#pragma unroll
        for (int h2 = 0; h2 < 2; ++h2) {
            float acc[32];
#pragma unroll
            for (int j = 0; j < 32; ++j) acc[j] = 0.f;
#pragma unroll
            for (int i = 0; i < 4; ++i)
#pragma unroll
                for (int j = 0; j < 8; ++j) {
                    float t = acc[i * 8 + j];
                    t = fmaf(fnx[h2 * 4 + i], fnx[j], t);
                    t = fmaf(fny[h2 * 4 + i], fny[j], t);
                    t = fmaf(fnz[h2 * 4 + i], fnz[j], t);
                    t = fmaf(fnw[h2 * 4 + i], fnw[j], t);
                    acc[i * 8 + j] = t;
                }
            BUTTERFLY32_ATOMIC(h2 * 32)
        }
    }
    // ---- Phase 2c: Wsg and Cross from ag/ah ----
    {
        float scg[8], off_g[8];
#pragma unroll
        for (int m = 0; m < 8; ++m) {
            float mean = stot[16 + m] * inv;
            float var  = stot[24 + m] * inv - mean * mean;
            float s = ggam[m] / sqrtf(var + 1e-5f);
            scg[m] = s; off_g[m] = gbet[m] - mean * s;
        }
        float gnx[8], gny[8], gnz[8], gnw[8];
#pragma unroll
        for (int m = 0; m < 8; ++m) {
            float t;
            t = fmaf(scg[m], ag[m].x, off_g[m]); gnx[m] = t > 0.f ? t : 0.f;
            t = fmaf(scg[m], ag[m].y, off_g[m]); gny[m] = t > 0.f ? t : 0.f;
            t = fmaf(scg[m], ag[m].z, off_g[m]); gnz[m] = t > 0.f ? t : 0.f;
            t = fmaf(scg[m], ag[m].w, off_g[m]); gnw[m] = t > 0.f ? t : 0.f;
        }
#pragma unroll
        for (int h2 = 0; h2 < 2; ++h2) {
            float acc[32];
#pragma unroll
            for (int j = 0; j < 32; ++j) acc[j] = 0.f;
#pragma unroll
            for (int i = 0; i < 4; ++i)
#pragma unroll
                for (int j = 0; j < 8; ++j) {
                    float t = acc[i * 8 + j];
                    t = fmaf(gnx[h2 * 4 + i], gnx[j], t);
                    t = fmaf(gny[h2 * 4 + i], gny[j], t);
                    t = fmaf(gnz[h2 * 4 + i], gnz[j], t);
                    t = fmaf(gnw[h2 * 4 + i], gnw[j], t);
                    acc[i * 8 + j] = t;
                }
            BUTTERFLY32_ATOMIC(64 + h2 * 32)
        }
#pragma unroll
        for (int h2 = 0; h2 < 2; ++h2) {   // Cross = hx^T gx (ah raw)
            float acc[32];
#pragma unroll
            for (int j = 0; j < 32; ++j) acc[j] = 0.f;
#pragma unroll
            for (int i = 0; i < 4; ++i)
#pragma unroll
                for (int j = 0; j < 8; ++j) {
                    float t = acc[i * 8 + j];
                    t = fmaf(ah[h2 * 4 + i].x, gnx[j], t);
                    t = fmaf(ah[h2 * 4 + i].y, gny[j], t);
                    t = fmaf(ah[h2 * 4 + i].z, gnz[j], t);
                    t = fmaf(ah[h2 * 4 + i].w, gnw[j], t);
                    acc[i * 8 + j] = t;
                }
            BUTTERFLY32_ATOMIC(128 + h2 * 32)
        }
    }
    __syncthreads();
    if (threadIdx.x < 192)
        ((float*)(wsb + OFF_PWSA_B))[blockIdx.x * 192 + threadIdx.x] = sacc[threadIdx.x];
}

// ---------------------------------------------------------------------------
// K2: fused power-iteration + rank-1 epilogue + residual (R12 structure,
// 16 chunk partials per batch). grid 1024 = 32 b * 16 n-tiles * 2 c-halves.
__global__ __launch_bounds__(256, 4) void k_out(const float* __restrict__ x,
        const float* __restrict__ fgam, const float* __restrict__ fbet,
        const float* __restrict__ vw, const float* __restrict__ vb,
        const float* __restrict__ v0f, const float* __restrict__ v0g,
        const char* __restrict__ wsb, float* __restrict__ out) {
    int bid = blockIdx.x;
    int b = bid >> 5, sub = bid & 31;
    int tile = sub & 15, ch0 = (sub >> 4) * 32;
    __shared__ float s_vfn[8], s_coef[8], s_w2[64];

    const float* pw = (const float*)(wsb + OFF_PWSA_B) + (size_t)b * 16 * 192;
    if (threadIdx.x < 16) {
        int grp = threadIdx.x >> 3, m = threadIdx.x & 7;
        float row[8];
#pragma unroll
        for (int k = 0; k < 8; ++k) {
            float s = 0.f;
#pragma unroll
            for (int ch = 0; ch < 16; ++ch) s += pw[ch * 192 + grp * 64 + m * 8 + k];
            row[k] = s;
        }
        float v = (grp == 0 ? v0f : v0g)[b * 8 + m];
        for (int it = 0; it < 30; ++it) {
            float t = 0.f;
#pragma unroll
            for (int k = 0; k < 8; ++k) t = fmaf(row[k], __shfl(v, k, 8), t);
            float s = t * t;
            s += __shfl_xor(s, 1, 8); s += __shfl_xor(s, 2, 8); s += __shfl_xor(s, 4, 8);
            v = t / sqrtf(s);
        }
        // ||W v||^2 = v^T Ws v
        float t = 0.f;
#pragma unroll
        for (int k = 0; k < 8; ++k) t = fmaf(row[k], __shfl(v, k, 8), t);
        float s = v * t;
        s += __shfl_xor(s, 1, 8); s += __shfl_xor(s, 2, 8); s += __shfl_xor(s, 4, 8);
        float invn = 1.f / sqrtf(s);
        if (grp == 0) {
            s_vfn[m] = v * invn;
        } else {
            float cf = 0.f;
#pragma unroll
            for (int k = 0; k < 8; ++k) {
                float cr = 0.f;
#pragma unroll
                for (int ch = 0; ch < 16; ++ch) cr += pw[ch * 192 + 128 + m * 8 + k];
                cf = fmaf(cr, __shfl(v, k, 8), cf);
            }
            s_coef[m] = cf * invn;
        }
    }
    __syncthreads();
    if (threadIdx.x < 64) {
        float acc = 0.f;
#pragma unroll
        for (int k = 0; k < 8; ++k) acc = fmaf(vw[threadIdx.x * 8 + k], s_coef[k], acc);
        s_w2[threadIdx.x] = acc;
    }
    __syncthreads();

    int n0 = tile * 1024 + threadIdx.x * 4;
    const float inv = 1.f / CNTF;
    const float* stats = (const float*)(wsb + OFF_STATS_B);
    const unsigned short* fx16 = (const unsigned short*)(wsb + OFF_FXP_B);

    float uf0 = 0.f, uf1 = 0.f, uf2 = 0.f, uf3 = 0.f;
#pragma unroll
    for (int m = 0; m < 8; ++m) {
        float mean = stats[m] * inv;
        float var  = stats[8 + m] * inv - mean * mean;
        float a    = fgam[m] / sqrtf(var + 1e-5f);
        float cc   = fbet[m] - mean * a;
        float vf   = s_vfn[m];
        u32x2 u = *(const u32x2*)(fx16 + (size_t)(b * 8 + m) * NSP + n0);
        float t0 = fmaf(a, lo16(u.x), cc); t0 = t0 > 0.f ? t0 : 0.f; uf0 = fmaf(vf, t0, uf0);
        float t1 = fmaf(a, hi16(u.x), cc); t1 = t1 > 0.f ? t1 : 0.f; uf1 = fmaf(vf, t1, uf1);
        float t2 = fmaf(a, lo16(u.y), cc); t2 = t2 > 0.f ? t2 : 0.f; uf2 = fmaf(vf, t2, uf2);
        float t3 = fmaf(a, hi16(u.y), cc); t3 = t3 > 0.f ? t3 : 0.f; uf3 = fmaf(vf, t3, uf3);
    }

    const float* xp = x   + (size_t)(b * CC + ch0) * NSP + n0;
    float*       op = out + (size_t)(b * CC + ch0) * NSP + n0;
#pragma unroll 8
    for (int c = 0; c < 32; ++c) {
        float w2c = s_w2[ch0 + c];
        float bc  = vb[ch0 + c];
        float4 xv = *(const float4*)(xp + (size_t)c * NSP);   // want the L3 hit
        f32x4 ov;
        ov.x = fmaf(uf0, w2c, xv.x + bc);
        ov.y = fmaf(uf1, w2c, xv.y + bc);
        ov.z = fmaf(uf2, w2c, xv.z + bc);
        ov.w = fmaf(uf3, w2c, xv.w + bc);
        __builtin_nontemporal_store(ov, (f32x4*)(op + (size_t)c * NSP));  // out never re-read
    }
}

// ---------------------------------------------------------------------------
extern "C" void kernel_launch(void* const* d_in, const int* in_sizes, int n_in,
                              void* d_out, int out_size, void* d_ws, size_t ws_size,
                              hipStream_t stream) {
    const float* x    = (const float*)d_in[0];
    const float* f_w  = (const float*)d_in[1];
    const float* f_b  = (const float*)d_in[2];
    const float* f_g  = (const float*)d_in[3];
    const float* f_be = (const float*)d_in[4];
    const float* g_w  = (const float*)d_in[5];
    const float* g_b  = (const float*)d_in[6];
    const float* g_g  = (const float*)d_in[7];
    const float* g_be = (const float*)d_in[8];
    const float* h_w  = (const float*)d_in[9];
    const float* h_b  = (const float*)d_in[10];
    const float* v_w  = (const float*)d_in[11];
    const float* v_b  = (const float*)d_in[12];
    const float* v0f  = (const float*)d_in[13];
    const float* v0g  = (const float*)d_in[14];
    char*  wsb = (char*)d_ws;
    float* out = (float*)d_out;

    // zero only the 4-byte grid-barrier counter
    (void)hipMemsetAsync(wsb + OFF_BAR_B, 0, 4, stream);

    k_fused1<<<NBLK1, 256, 0, stream>>>(x, f_w, g_w, h_w, f_b, g_b, h_b,
                                        f_g, f_be, g_g, g_be, wsb);
    k_out  <<<1024,  256, 0, stream>>>(x, f_g, f_be, v_w, v_b, v0f, v0g, wsb, out);
}

// Round 17
// 102.138 us; speedup vs baseline: 2.4083x; 2.4083x over previous
//
#include <hip/hip_runtime.h>

// Problem constants
#define BB   32
#define CC   64
#define MM   8
#define NSP  16384            // H*W = 128*128
#define CNTF 524288.0f        // B*N, BN statistics count

typedef float f32x4 __attribute__((ext_vector_type(4)));
typedef unsigned int u32x2 __attribute__((ext_vector_type(2)));

// Workspace layout (BYTE offsets). Intermediates stored as bf16.
// No atomics anywhere -> no memset dispatch needed.
#define OFF_FXP_B    0ull                              // [B][M][N] bf16, 8.39 MB
#define OFF_GXP_B    8388608ull
#define OFF_HX_B     16777216ull
#define OFF_PSTATS_B 25165824ull                       // [512][32] f32 per-block stats partials
#define OFF_PWSA_B   (OFF_PSTATS_B + 512ull*32*4)      // [32][3][8][64] f32 gram partials
#define OFF_STATS_B  (OFF_PWSA_B + 32ull*3*8*64*4)     // [32] f32 final stats (k_gram bid0)

#define AXPY(A, WS, XV) \
    (A).x = fmaf((WS), (XV).x, (A).x); (A).y = fmaf((WS), (XV).y, (A).y); \
    (A).z = fmaf((WS), (XV).z, (A).z); (A).w = fmaf((WS), (XV).w, (A).w);

// bf16 pack (round-to-nearest-even) / unpack helpers
__device__ __forceinline__ unsigned pk_bf2(float a, float b) {
    unsigned ua = __float_as_uint(a); ua += 0x7FFFu + ((ua >> 16) & 1u);
    unsigned ub = __float_as_uint(b); ub += 0x7FFFu + ((ub >> 16) & 1u);
    return (ua >> 16) | (ub & 0xFFFF0000u);
}
__device__ __forceinline__ float lo16(unsigned u) { return __uint_as_float(u << 16); }
__device__ __forceinline__ float hi16(unsigned u) { return __uint_as_float(u & 0xFFFF0000u); }

// ---------------------------------------------------------------------------
// K1: fused pack + conv + BN-stats. float4 per thread (16 B/lane), LDS
// weights, launch_bounds(256,2) (proven: no spill, ~110-reg live set).
// Stats partials stored per block — no atomics.
__global__ __launch_bounds__(256, 2) void k_conv(const float* __restrict__ x,
        const float* __restrict__ fw, const float* __restrict__ gw,
        const float* __restrict__ hw,
        const float* __restrict__ fb, const float* __restrict__ gb,
        const float* __restrict__ hb, char* __restrict__ wsb) {
    __shared__ float wt[1536];          // [c][24]: f0..7 g0..7 h0..7
    __shared__ float sred[4][32];
    for (int i = threadIdx.x; i < 1536; i += 256) {
        int c = i / 24, k = i % 24;
        wt[i] = (k < 8) ? fw[k * 64 + c]
              : (k < 16) ? gw[(k - 8) * 64 + c]
                         : hw[(k - 16) * 64 + c];
    }
    __syncthreads();

    int g  = blockIdx.x * 256 + threadIdx.x;   // quad index (4 n per thread)
    int b  = g >> 12;                          // 4096 quads per batch
    int n0 = (g & 4095) * 4;

    const float* xp = x + (size_t)b * CC * NSP + n0;

    float4 af[8], ag[8], ah[8];
#pragma unroll
    for (int m = 0; m < 8; ++m) {
        float bf = fb[m], bg = gb[m], bh = hb[m];
        af[m] = make_float4(bf, bf, bf, bf);
        ag[m] = make_float4(bg, bg, bg, bg);
        ah[m] = make_float4(bh, bh, bh, bh);
    }

#pragma unroll 8
    for (int c = 0; c < 64; ++c) {
        float4 xv = *(const float4*)(xp + (size_t)c * NSP);
        const float4* w4 = (const float4*)(&wt[c * 24]);
        float4 wf0 = w4[0], wf1 = w4[1], wg0 = w4[2], wg1 = w4[3], wh0 = w4[4], wh1 = w4[5];
        AXPY(af[0], wf0.x, xv); AXPY(af[1], wf0.y, xv); AXPY(af[2], wf0.z, xv); AXPY(af[3], wf0.w, xv);
        AXPY(af[4], wf1.x, xv); AXPY(af[5], wf1.y, xv); AXPY(af[6], wf1.z, xv); AXPY(af[7], wf1.w, xv);
        AXPY(ag[0], wg0.x, xv); AXPY(ag[1], wg0.y, xv); AXPY(ag[2], wg0.z, xv); AXPY(ag[3], wg0.w, xv);
        AXPY(ag[4], wg1.x, xv); AXPY(ag[5], wg1.y, xv); AXPY(ag[6], wg1.z, xv); AXPY(ag[7], wg1.w, xv);
        AXPY(ah[0], wh0.x, xv); AXPY(ah[1], wh0.y, xv); AXPY(ah[2], wh0.z, xv); AXPY(ah[3], wh0.w, xv);
        AXPY(ah[4], wh1.x, xv); AXPY(ah[5], wh1.y, xv); AXPY(ah[6], wh1.z, xv); AXPY(ah[7], wh1.w, xv);
    }

    unsigned short* fx16 = (unsigned short*)(wsb + OFF_FXP_B);
    unsigned short* gx16 = (unsigned short*)(wsb + OFF_GXP_B);
    unsigned short* hx16 = (unsigned short*)(wsb + OFF_HX_B);
    size_t base = (size_t)b * MM * NSP + n0;
#pragma unroll
    for (int m = 0; m < 8; ++m) {
        u32x2 pf; pf.x = pk_bf2(af[m].x, af[m].y); pf.y = pk_bf2(af[m].z, af[m].w);
        u32x2 pg; pg.x = pk_bf2(ag[m].x, ag[m].y); pg.y = pk_bf2(ag[m].z, ag[m].w);
        u32x2 ph; ph.x = pk_bf2(ah[m].x, ah[m].y); ph.y = pk_bf2(ah[m].z, ah[m].w);
        *(u32x2*)(fx16 + base + (size_t)m * NSP) = pf;
        *(u32x2*)(gx16 + base + (size_t)m * NSP) = pg;
        *(u32x2*)(hx16 + base + (size_t)m * NSP) = ph;
    }

    // BN stats from fp32 registers -> per-block partial (plain store)
    int wid = threadIdx.x >> 6, lane = threadIdx.x & 63;
#pragma unroll
    for (int m = 0; m < 8; ++m) {
        float fs = af[m].x + af[m].y + af[m].z + af[m].w;
        float fq = af[m].x * af[m].x + af[m].y * af[m].y + af[m].z * af[m].z + af[m].w * af[m].w;
        float gs = ag[m].x + ag[m].y + ag[m].z + ag[m].w;
        float gq = ag[m].x * ag[m].x + ag[m].y * ag[m].y + ag[m].z * ag[m].z + ag[m].w * ag[m].w;
#pragma unroll
        for (int o = 1; o < 64; o <<= 1) {
            fs += __shfl_xor(fs, o); fq += __shfl_xor(fq, o);
            gs += __shfl_xor(gs, o); gq += __shfl_xor(gq, o);
        }
        if (lane == 0) {
            sred[wid][m] = fs; sred[wid][8 + m] = fq;
            sred[wid][16 + m] = gs; sred[wid][24 + m] = gq;
        }
    }
    __syncthreads();
    if (threadIdx.x < 32) {
        float t = sred[0][threadIdx.x] + sred[1][threadIdx.x]
                + sred[2][threadIdx.x] + sred[3][threadIdx.x];
        ((float*)(wsb + OFF_PSTATS_B))[blockIdx.x * 32 + threadIdx.x] = t;
    }
}

// ---------------------------------------------------------------------------
// K2: per-batch 8x8 Gram matrices from bf16 intermediates.
// Prologue reduces the 512 stats partials (L2-hot, ~0.7us); bid 0 publishes
// final stats. Gram partial per (b,which,chunk) slot — plain stores.
__global__ __launch_bounds__(256) void k_gram(
        const float* __restrict__ fgam, const float* __restrict__ fbet,
        const float* __restrict__ ggam, const float* __restrict__ gbet,
        char* __restrict__ wsb) {
    int bid = blockIdx.x;
    int chunk = bid & 7, which = (bid >> 3) % 3, b = bid / 24;

    // ---- stats reduction prologue ----
    __shared__ float sst[8][32];
    __shared__ float stot[32];
    {
        int t32 = threadIdx.x & 31, seg = threadIdx.x >> 5;   // 8 segs x 64 blocks
        const float* ps = (const float*)(wsb + OFF_PSTATS_B);
        float s = 0.f;
#pragma unroll 8
        for (int i = 0; i < 64; ++i) s += ps[(seg * 64 + i) * 32 + t32];
        sst[seg][t32] = s;
    }
    __syncthreads();
    if (threadIdx.x < 32) {
        float t = 0.f;
#pragma unroll
        for (int w = 0; w < 8; ++w) t += sst[w][threadIdx.x];
        stot[threadIdx.x] = t;
        if (bid == 0) ((float*)(wsb + OFF_STATS_B))[threadIdx.x] = t;
    }
    __syncthreads();

    const float* st  = stot + (which == 0 ? 0 : 16);
    const float* gam = (which == 0) ? fgam : ggam;
    const float* bet = (which == 0) ? fbet : gbet;
    const float inv = 1.f / CNTF;
    float a[8], ccf[8];
#pragma unroll
    for (int m = 0; m < 8; ++m) {
        float mean = st[m] * inv;
        float var  = st[8 + m] * inv - mean * mean;
        float sc   = gam[m] / sqrtf(var + 1e-5f);
        a[m] = sc; ccf[m] = bet[m] - mean * sc;
    }

    const unsigned short* src = (const unsigned short*)
        (wsb + (which == 0 ? OFF_FXP_B : OFF_GXP_B)) + (size_t)b * MM * NSP;
    const unsigned short* hsrc = (const unsigned short*)
        (wsb + OFF_HX_B) + (size_t)b * MM * NSP;

    float acc[64];
#pragma unroll
    for (int j = 0; j < 64; ++j) acc[j] = 0.f;

#pragma unroll
    for (int i = 0; i < 2; ++i) {
        int n = (chunk * 512 + i * 256 + threadIdx.x) * 4;
        float4 vv[8], hh[8];
#pragma unroll
        for (int m = 0; m < 8; ++m) {
            u32x2 u = *(const u32x2*)(src + (size_t)m * NSP + n);
            float4 t;
            t.x = fmaf(a[m], lo16(u.x), ccf[m]); t.x = t.x > 0.f ? t.x : 0.f;
            t.y = fmaf(a[m], hi16(u.x), ccf[m]); t.y = t.y > 0.f ? t.y : 0.f;
            t.z = fmaf(a[m], lo16(u.y), ccf[m]); t.z = t.z > 0.f ? t.z : 0.f;
            t.w = fmaf(a[m], hi16(u.y), ccf[m]); t.w = t.w > 0.f ? t.w : 0.f;
            vv[m] = t;
        }
        if (which == 2) {
#pragma unroll
            for (int m = 0; m < 8; ++m) {
                u32x2 u = *(const u32x2*)(hsrc + (size_t)m * NSP + n);
                hh[m] = make_float4(lo16(u.x), hi16(u.x), lo16(u.y), hi16(u.y));
            }
        } else {
#pragma unroll
            for (int m = 0; m < 8; ++m) hh[m] = vv[m];
        }
#pragma unroll
        for (int m2 = 0; m2 < 8; ++m2)
#pragma unroll
            for (int k = 0; k < 8; ++k) {
                float t = acc[m2 * 8 + k];
                t = fmaf(hh[m2].x, vv[k].x, t);
                t = fmaf(hh[m2].y, vv[k].y, t);
                t = fmaf(hh[m2].z, vv[k].z, t);
                t = fmaf(hh[m2].w, vv[k].w, t);
                acc[m2 * 8 + k] = t;
            }
    }

    // reduce-scatter butterfly across the wave (static register indices)
    int lane = threadIdx.x & 63;
#pragma unroll
    for (int s2 = 0; s2 < 6; ++s2) {
        int half = 32 >> s2;
        int up = (lane >> s2) & 1;
#pragma unroll
        for (int j = 0; j < 32; ++j) {
            if (j >= half) break;
            float send = up ? acc[j] : acc[j + half];
            float recv = __shfl_xor(send, 1 << s2);
            float keep = up ? acc[j + half] : acc[j];
            acc[j] = keep + recv;
        }
    }
    __shared__ float sacc[64];
    if (threadIdx.x < 64) sacc[threadIdx.x] = 0.f;
    __syncthreads();
    int rev = __brev((unsigned)lane) >> 26;
    atomicAdd(&sacc[rev], acc[0]);     // LDS atomic only (4 waves)
    __syncthreads();
    float* pw = (float*)(wsb + OFF_PWSA_B) + (((size_t)b * 3 + which) * 8 + chunk) * 64;
    if (threadIdx.x < 64) pw[threadIdx.x] = sacc[threadIdx.x];
}

// ---------------------------------------------------------------------------
// K3: fused power-iteration + rank-1 epilogue + residual.
// Ws/Cross loaded as 8-chunk partial sums; stats from k_gram bid0.
// grid 1024 = 32 b * 16 n-tiles * 2 c-halves.
__global__ __launch_bounds__(256, 4) void k_out(const float* __restrict__ x,
        const float* __restrict__ fgam, const float* __restrict__ fbet,
        const float* __restrict__ vw, const float* __restrict__ vb,
        const float* __restrict__ v0f, const float* __restrict__ v0g,
        const char* __restrict__ wsb, float* __restrict__ out) {
    int bid = blockIdx.x;
    int b = bid >> 5, sub = bid & 31;
    int tile = sub & 15, ch0 = (sub >> 4) * 32;
    __shared__ float s_vfn[8], s_coef[8], s_w2[64];

    const float* pw = (const float*)(wsb + OFF_PWSA_B) + (size_t)b * 3 * 8 * 64;
    if (threadIdx.x < 16) {
        int grp = threadIdx.x >> 3, m = threadIdx.x & 7;
        float row[8];
#pragma unroll
        for (int k = 0; k < 8; ++k) {
            float s = 0.f;
#pragma unroll
            for (int ch = 0; ch < 8; ++ch) s += pw[(grp * 8 + ch) * 64 + m * 8 + k];
            row[k] = s;
        }
        float v = (grp == 0 ? v0f : v0g)[b * 8 + m];
        for (int it = 0; it < 30; ++it) {
            float t = 0.f;
#pragma unroll
            for (int k = 0; k < 8; ++k) t = fmaf(row[k], __shfl(v, k, 8), t);
            float s = t * t;
            s += __shfl_xor(s, 1, 8); s += __shfl_xor(s, 2, 8); s += __shfl_xor(s, 4, 8);
            v = t / sqrtf(s);
        }
        // ||W v||^2 = v^T Ws v
        float t = 0.f;
#pragma unroll
        for (int k = 0; k < 8; ++k) t = fmaf(row[k], __shfl(v, k, 8), t);
        float s = v * t;
        s += __shfl_xor(s, 1, 8); s += __shfl_xor(s, 2, 8); s += __shfl_xor(s, 4, 8);
        float invn = 1.f / sqrtf(s);
        if (grp == 0) {
            s_vfn[m] = v * invn;
        } else {
            float cf = 0.f;
#pragma unroll
            for (int k = 0; k < 8; ++k) {
                float cr = 0.f;
#pragma unroll
                for (int ch = 0; ch < 8; ++ch) cr += pw[(2 * 8 + ch) * 64 + m * 8 + k];
                cf = fmaf(cr, __shfl(v, k, 8), cf);
            }
            s_coef[m] = cf * invn;
        }
    }
    __syncthreads();
    if (threadIdx.x < 64) {
        float acc = 0.f;
#pragma unroll
        for (int k = 0; k < 8; ++k) acc = fmaf(vw[threadIdx.x * 8 + k], s_coef[k], acc);
        s_w2[threadIdx.x] = acc;
    }
    __syncthreads();

    int n0 = tile * 1024 + threadIdx.x * 4;
    const float inv = 1.f / CNTF;
    const float* stats = (const float*)(wsb + OFF_STATS_B);
    const unsigned short* fx16 = (const unsigned short*)(wsb + OFF_FXP_B);

    float uf0 = 0.f, uf1 = 0.f, uf2 = 0.f, uf3 = 0.f;
#pragma unroll
    for (int m = 0; m < 8; ++m) {
        float mean = stats[m] * inv;
        float var  = stats[8 + m] * inv - mean * mean;
        float a    = fgam[m] / sqrtf(var + 1e-5f);
        float cc   = fbet[m] - mean * a;
        float vf   = s_vfn[m];
        u32x2 u = *(const u32x2*)(fx16 + (size_t)(b * 8 + m) * NSP + n0);
        float t0 = fmaf(a, lo16(u.x), cc); t0 = t0 > 0.f ? t0 : 0.f; uf0 = fmaf(vf, t0, uf0);
        float t1 = fmaf(a, hi16(u.x), cc); t1 = t1 > 0.f ? t1 : 0.f; uf1 = fmaf(vf, t1, uf1);
        float t2 = fmaf(a, lo16(u.y), cc); t2 = t2 > 0.f ? t2 : 0.f; uf2 = fmaf(vf, t2, uf2);
        float t3 = fmaf(a, hi16(u.y), cc); t3 = t3 > 0.f ? t3 : 0.f; uf3 = fmaf(vf, t3, uf3);
    }

    const float* xp = x   + (size_t)(b * CC + ch0) * NSP + n0;
    float*       op = out + (size_t)(b * CC + ch0) * NSP + n0;
#pragma unroll 8
    for (int c = 0; c < 32; ++c) {
        float w2c = s_w2[ch0 + c];
        float bc  = vb[ch0 + c];
        float4 xv = *(const float4*)(xp + (size_t)c * NSP);   // want the L3 hit
        f32x4 ov;
        ov.x = fmaf(uf0, w2c, xv.x + bc);
        ov.y = fmaf(uf1, w2c, xv.y + bc);
        ov.z = fmaf(uf2, w2c, xv.z + bc);
        ov.w = fmaf(uf3, w2c, xv.w + bc);
        __builtin_nontemporal_store(ov, (f32x4*)(op + (size_t)c * NSP));  // out never re-read
    }
}

// ---------------------------------------------------------------------------
extern "C" void kernel_launch(void* const* d_in, const int* in_sizes, int n_in,
                              void* d_out, int out_size, void* d_ws, size_t ws_size,
                              hipStream_t stream) {
    const float* x    = (const float*)d_in[0];
    const float* f_w  = (const float*)d_in[1];
    const float* f_b  = (const float*)d_in[2];
    const float* f_g  = (const float*)d_in[3];
    const float* f_be = (const float*)d_in[4];
    const float* g_w  = (const float*)d_in[5];
    const float* g_b  = (const float*)d_in[6];
    const float* g_g  = (const float*)d_in[7];
    const float* g_be = (const float*)d_in[8];
    const float* h_w  = (const float*)d_in[9];
    const float* h_b  = (const float*)d_in[10];
    const float* v_w  = (const float*)d_in[11];
    const float* v_b  = (const float*)d_in[12];
    const float* v0f  = (const float*)d_in[13];
    const float* v0g  = (const float*)d_in[14];
    char*  wsb = (char*)d_ws;
    float* out = (float*)d_out;

    // no memset: all cross-kernel accumulators are plain-store partials
    k_conv<<<512,  256, 0, stream>>>(x, f_w, g_w, h_w, f_b, g_b, h_b, wsb);
    k_gram<<<768,  256, 0, stream>>>(f_g, f_be, g_g, g_be, wsb);
    k_out <<<1024, 256, 0, stream>>>(x, f_g, f_be, v_w, v_b, v0f, v0g, wsb, out);
}